// Round 1
// baseline (13434.062 us; speedup 1.0000x reference)
//
#include <hip/hip_runtime.h>
#include <hip/hip_bf16.h>
#include <math.h>

typedef __bf16 bf16x8 __attribute__((ext_vector_type(8)));
typedef float f32x4 __attribute__((ext_vector_type(4)));

#define MFMA16(a,b,c) __builtin_amdgcn_mfma_f32_16x16x32_bf16(a,b,c,0,0,0)

constexpr int BATCH = 1024, SEQ = 80, EMB = 100, U = 512, G = 1536;
constexpr int KX = 128;          // padded K for the embedding GEMM (100 -> 128)
constexpr int BT = 16;           // batch rows per block
constexpr int NW = 8, NT = NW * 64;
constexpr int HP = 520;          // padded LDS row stride for h (bf16 elems): 1040B = 65*16, 2-way banks
constexpr int XP = 136;          // padded LDS row stride for x: 272B = 17*16

// in: [K][N] row-major f32 ; out: [N][Kp] bf16 (transposed, zero-padded K)
__global__ void k_conv_transpose(const float* __restrict__ in, __bf16* __restrict__ out,
                                 int N, int Kp, int Klim) {
  int idx = blockIdx.x * 256 + threadIdx.x;
  int total = N * (Kp / 8);
  if (idx >= total) return;
  int n = idx % N;       // consecutive threads -> consecutive n: coalesced reads
  int kb = idx / N;
  bf16x8 v;
#pragma unroll
  for (int j = 0; j < 8; ++j) {
    int k = kb * 8 + j;
    v[j] = (k < Klim) ? (__bf16)in[(size_t)k * N + n] : (__bf16)0.f;
  }
  *(bf16x8*)(out + (size_t)n * Kp + kb * 8) = v;
}

__global__ void k_conv_bf16(const float* __restrict__ in, __bf16* __restrict__ out, int n) {
  int idx = blockIdx.x * 256 + threadIdx.x;
  if (idx < n) out[idx] = (__bf16)in[idx];
}

__device__ __forceinline__ float sigmoidf_(float x) { return 1.f / (1.f + __expf(-x)); }

// Fused 2-layer GRU. Block b owns batch rows [16b, 16b+16). Wave w owns units [64w, 64w+64):
// its 12 MFMA N-tiles are the z/r/n gate columns for those units, so gate math is in-register.
// A-operand (h / x) from LDS; B-operand (transposed bf16 weights) streamed from global (L2).
__global__ __launch_bounds__(NT, 2)
void k_gru(const int* __restrict__ tokens, const __bf16* __restrict__ emb,
           const __bf16* __restrict__ Wx1t, const __bf16* __restrict__ Wh1t,
           const __bf16* __restrict__ Wx2t, const __bf16* __restrict__ Wh2t,
           const float* __restrict__ b1, const float* __restrict__ b2,
           const float* __restrict__ Wfc, const float* __restrict__ bfc,
           float* __restrict__ out) {
  __shared__ __attribute__((aligned(16))) __bf16 xs[BT * XP];
  __shared__ __attribute__((aligned(16))) __bf16 h1s[2][BT * HP];  // double buffered
  __shared__ __attribute__((aligned(16))) __bf16 h2s[BT * HP];     // single buffered

  const int tid = threadIdx.x;
  const int wave = tid >> 6, lane = tid & 63;
  const int ln = lane & 15, quad = lane >> 4;
  const int u0 = wave * 64;
  const int rowbase = blockIdx.x * BT;

  for (int i = tid; i < BT * HP; i += NT) {
    h1s[0][i] = (__bf16)0.f; h1s[1][i] = (__bf16)0.f; h2s[i] = (__bf16)0.f;
  }
  float h1o[4][4] = {}, h2o[4][4] = {};  // this wave's owned h values, f32

  // col base per N-tile j: gate (j>>2) in {z,r,n}, unit sub-tile (j&3)
  int cb[12];
#pragma unroll
  for (int j = 0; j < 12; ++j) cb[j] = (j >> 2) * U + u0 + (j & 3) * 16;

  // lane-dependent parts of the B-fragment offsets (elements)
  const int voffU = ln * U + quad * 8;   // for K=512 matrices
  const int voffX = ln * KX + quad * 8;  // for Wx1t

  __syncthreads();

  int cur = 0;
#pragma unroll 1
  for (int t = 0; t < SEQ; ++t) {
    // ---- stage x_t (16 rows x 100, zero-padded to 128) ----
    {
      int r = tid >> 5, c4 = (tid & 31) * 4;
      int tok = tokens[(rowbase + r) * SEQ + t];
      __bf16 v0 = (__bf16)0.f, v1 = v0, v2 = v0, v3 = v0;
      if (c4 < EMB) {
        const __bf16* e = emb + (size_t)tok * EMB + c4;
        v0 = e[0]; v1 = e[1]; v2 = e[2]; v3 = e[3];
      }
      __bf16* xp = xs + r * XP + c4;
      xp[0] = v0; xp[1] = v1; xp[2] = v2; xp[3] = v3;
    }
    __syncthreads();

    // ---- layer 1 ----
    f32x4 agx[12], agh[12];
#pragma unroll
    for (int j = 0; j < 12; ++j) {
      float bx = b1[cb[j] + ln], bh = b1[G + cb[j] + ln];
      f32x4 vx = {bx, bx, bx, bx}; f32x4 vh = {bh, bh, bh, bh};
      agx[j] = vx; agh[j] = vh;
    }
#pragma unroll
    for (int ks = 0; ks < KX / 32; ++ks) {
      bf16x8 a = *(const bf16x8*)(xs + ln * XP + ks * 32 + quad * 8);
#pragma unroll
      for (int j = 0; j < 12; ++j) {
        bf16x8 b = *(const bf16x8*)(Wx1t + (size_t)cb[j] * KX + voffX + ks * 32);
        agx[j] = MFMA16(a, b, agx[j]);
      }
    }
#pragma unroll 4
    for (int ks = 0; ks < U / 32; ++ks) {
      bf16x8 a = *(const bf16x8*)(h1s[cur] + ln * HP + ks * 32 + quad * 8);
#pragma unroll
      for (int j = 0; j < 12; ++j) {
        bf16x8 b = *(const bf16x8*)(Wh1t + (size_t)cb[j] * U + voffU + ks * 32);
        agh[j] = MFMA16(a, b, agh[j]);
      }
    }
#pragma unroll
    for (int j = 0; j < 4; ++j)
#pragma unroll
      for (int i = 0; i < 4; ++i) {
        float z = sigmoidf_(agx[j][i] + agh[j][i]);
        float r = sigmoidf_(agx[4 + j][i] + agh[4 + j][i]);
        float hh = tanhf(agx[8 + j][i] + r * agh[8 + j][i]);
        float h = z * h1o[j][i] + (1.f - z) * hh;
        h1o[j][i] = h;
        h1s[cur ^ 1][(quad * 4 + i) * HP + u0 + j * 16 + ln] = (__bf16)h;
      }
    __syncthreads();

    // ---- layer 2 (x input = h1_new just written) ----
#pragma unroll
    for (int j = 0; j < 12; ++j) {
      float bx = b2[cb[j] + ln], bh = b2[G + cb[j] + ln];
      f32x4 vx = {bx, bx, bx, bx}; f32x4 vh = {bh, bh, bh, bh};
      agx[j] = vx; agh[j] = vh;
    }
#pragma unroll 4
    for (int ks = 0; ks < U / 32; ++ks) {
      bf16x8 a = *(const bf16x8*)(h1s[cur ^ 1] + ln * HP + ks * 32 + quad * 8);
#pragma unroll
      for (int j = 0; j < 12; ++j) {
        bf16x8 b = *(const bf16x8*)(Wx2t + (size_t)cb[j] * U + voffU + ks * 32);
        agx[j] = MFMA16(a, b, agx[j]);
      }
    }
#pragma unroll 4
    for (int ks = 0; ks < U / 32; ++ks) {
      bf16x8 a = *(const bf16x8*)(h2s + ln * HP + ks * 32 + quad * 8);
#pragma unroll
      for (int j = 0; j < 12; ++j) {
        bf16x8 b = *(const bf16x8*)(Wh2t + (size_t)cb[j] * U + voffU + ks * 32);
        agh[j] = MFMA16(a, b, agh[j]);
      }
    }
    float hn[4][4];
#pragma unroll
    for (int j = 0; j < 4; ++j)
#pragma unroll
      for (int i = 0; i < 4; ++i) {
        float z = sigmoidf_(agx[j][i] + agh[j][i]);
        float r = sigmoidf_(agx[4 + j][i] + agh[4 + j][i]);
        float hh = tanhf(agx[8 + j][i] + r * agh[8 + j][i]);
        hn[j][i] = z * h2o[j][i] + (1.f - z) * hh;
        h2o[j][i] = hn[j][i];
      }
    __syncthreads();  // all waves done reading h2s (single-buffered)
#pragma unroll
    for (int j = 0; j < 4; ++j)
#pragma unroll
      for (int i = 0; i < 4; ++i)
        h2s[(quad * 4 + i) * HP + u0 + j * 16 + ln] = (__bf16)hn[j][i];
    __syncthreads();

    cur ^= 1;
  }

  // ---- epilogue: out[row] = sigmoid(h2 . Wfc + bfc) ----
  {
    int r = wave * 2 + (lane >> 5);
    int l32 = lane & 31;
    float s = 0.f;
    for (int k = l32; k < U; k += 32) s += (float)h2s[r * HP + k] * Wfc[k];
#pragma unroll
    for (int off = 16; off; off >>= 1) s += __shfl_down(s, off, 32);
    if (l32 == 0) out[rowbase + r] = sigmoidf_(s + bfc[0]);
  }
}

extern "C" void kernel_launch(void* const* d_in, const int* in_sizes, int n_in,
                              void* d_out, int out_size, void* d_ws, size_t ws_size,
                              hipStream_t stream) {
  const int*   tokens = (const int*)d_in[0];
  const float* emb    = (const float*)d_in[1];
  const float* Wx1 = (const float*)d_in[2];
  const float* Wh1 = (const float*)d_in[3];
  const float* b1  = (const float*)d_in[4];
  const float* Wx2 = (const float*)d_in[5];
  const float* Wh2 = (const float*)d_in[6];
  const float* b2  = (const float*)d_in[7];
  const float* Wfc = (const float*)d_in[8];
  const float* bfc = (const float*)d_in[9];
  float* out = (float*)d_out;

  // ws layout (all 16B aligned): bf16 transposed weights + bf16 embedding (~7.1 MB)
  __bf16* Wx1t  = (__bf16*)d_ws;           // [1536][128]
  __bf16* Wh1t  = Wx1t + 1536 * 128;       // [1536][512]
  __bf16* Wx2t  = Wh1t + 1536 * 512;       // [1536][512]
  __bf16* Wh2t  = Wx2t + 1536 * 512;       // [1536][512]
  __bf16* emb16 = Wh2t + 1536 * 512;       // [10000][100]

  k_conv_transpose<<<(1536 * 16 + 255) / 256, 256, 0, stream>>>(Wx1, Wx1t, 1536, 128, 100);
  k_conv_transpose<<<(1536 * 64 + 255) / 256, 256, 0, stream>>>(Wh1, Wh1t, 1536, 512, 512);
  k_conv_transpose<<<(1536 * 64 + 255) / 256, 256, 0, stream>>>(Wx2, Wx2t, 1536, 512, 512);
  k_conv_transpose<<<(1536 * 64 + 255) / 256, 256, 0, stream>>>(Wh2, Wh2t, 1536, 512, 512);
  k_conv_bf16<<<(1000000 + 255) / 256, 256, 0, stream>>>(emb, emb16, 1000000);

  k_gru<<<BATCH / BT, NT, 0, stream>>>(tokens, emb16, Wx1t, Wh1t, Wx2t, Wh2t,
                                       b1, b2, Wfc, bfc, out);
}

// Round 2
// 4481.721 us; speedup vs baseline: 2.9975x; 2.9975x over previous
//
#include <hip/hip_runtime.h>
#include <hip/hip_bf16.h>
#include <math.h>

typedef __bf16 bf16x8 __attribute__((ext_vector_type(8)));
typedef float f32x4 __attribute__((ext_vector_type(4)));

#define MFMA16(a,b,c) __builtin_amdgcn_mfma_f32_16x16x32_bf16(a,b,c,0,0,0)

constexpr int BATCH = 1024, SEQ = 80, EMB = 100, U = 512, G = 1536;
constexpr int KX = 128;   // padded embed K
constexpr int XP = 136;   // LDS x stride (bf16 elems): 272B, 2-way bank alias only

// in: [K][N] row-major f32 ; out: [N][Kp] bf16 (transposed, zero-padded K)
__global__ void k_conv_transpose(const float* __restrict__ in, __bf16* __restrict__ out,
                                 int N, int Kp, int Klim) {
  int idx = blockIdx.x * 256 + threadIdx.x;
  int total = N * (Kp / 8);
  if (idx >= total) return;
  int n = idx % N;
  int kb = idx / N;
  bf16x8 v;
#pragma unroll
  for (int j = 0; j < 8; ++j) {
    int k = kb * 8 + j;
    v[j] = (k < Klim) ? (__bf16)in[(size_t)k * N + n] : (__bf16)0.f;
  }
  *(bf16x8*)(out + (size_t)n * Kp + kb * 8) = v;
}

// emb [10000][100] f32 -> [10000][128] bf16 zero-padded
__global__ void k_emb_pad(const float* __restrict__ in, __bf16* __restrict__ out) {
  int idx = blockIdx.x * 256 + threadIdx.x;
  if (idx >= 10000 * KX) return;
  int r = idx >> 7, c = idx & 127;
  out[idx] = (c < EMB) ? (__bf16)in[r * EMB + c] : (__bf16)0.f;
}

__device__ __forceinline__ float sigmoidf_(float x) { return 1.f / (1.f + __expf(-x)); }

// Pipelined GRU super-step s: blocks [0,128) = layer-1 @ t=s (if s<80),
// blocks [128,256) = layer-2 @ t=s-1 (if s>=1).
// Block tile: 128 batch rows (rg, 8 groups) x 32 units (cg, 16 groups), all 3 gates.
// Wave w owns rows [rg*128 + w*16, +16). n-gate uses split accumulators (xh vs hn).
__global__ __launch_bounds__(512, 2)
void k_step(int s,
            const int* __restrict__ tokens, const __bf16* __restrict__ embp,
            const __bf16* __restrict__ Wx1t, const __bf16* __restrict__ Wh1t,
            const __bf16* __restrict__ Wx2t, const __bf16* __restrict__ Wh2t,
            const float* __restrict__ b1, const float* __restrict__ b2,
            const __bf16* __restrict__ h1r, __bf16* __restrict__ h1w,
            const __bf16* __restrict__ h2r, __bf16* __restrict__ h2w,
            float* __restrict__ h1f, float* __restrict__ h2f) {
  __shared__ __attribute__((aligned(16))) __bf16 xs[128 * XP];

  const int bid = blockIdx.x, tid = threadIdx.x;
  const bool is2 = bid >= 128;
  if (is2 && s == 0) return;
  if (!is2 && s == SEQ) return;
  const int lb = is2 ? bid - 128 : bid;
  const int wv = tid >> 6, lane = tid & 63, ln = lane & 15, quad = lane >> 4;
  const int rg = lb & 7, cg = lb >> 3;
  const int r0 = rg * 128, u0 = cg * 32;
  const int rw = r0 + wv * 16;

  const f32x4 z4 = {0.f, 0.f, 0.f, 0.f};
  f32x4 az[2], ar[2], anh[2], anx[2];
#pragma unroll
  for (int j = 0; j < 2; ++j) { az[j] = z4; ar[j] = z4; anh[j] = z4; anx[j] = z4; }

  const int cz0 = u0, cr0 = U + u0, cn0 = 2 * U + u0;

  if (!is2) {
    // ---- stage x_t = emb[tok] into LDS (128 rows x 128 cols bf16) ----
    {
      int r = tid >> 2, seg = tid & 3;
      int tok = tokens[(r0 + r) * SEQ + s];
      const bf16x8* src = (const bf16x8*)(embp + (size_t)tok * KX + seg * 32);
      bf16x8* dst = (bf16x8*)(xs + r * XP + seg * 32);
      dst[0] = src[0]; dst[1] = src[1]; dst[2] = src[2]; dst[3] = src[3];
    }
    __syncthreads();
    // ---- h-part: K=512 over Wh1t ----
#pragma unroll 4
    for (int ks = 0; ks < 16; ++ks) {
      int k = ks * 32 + quad * 8;
      bf16x8 a = *(const bf16x8*)(h1r + (size_t)(rw + ln) * U + k);
#pragma unroll
      for (int j = 0; j < 2; ++j) {
        az[j]  = MFMA16(a, *(const bf16x8*)(Wh1t + (size_t)(cz0 + j * 16 + ln) * U + k), az[j]);
        ar[j]  = MFMA16(a, *(const bf16x8*)(Wh1t + (size_t)(cr0 + j * 16 + ln) * U + k), ar[j]);
        anh[j] = MFMA16(a, *(const bf16x8*)(Wh1t + (size_t)(cn0 + j * 16 + ln) * U + k), anh[j]);
      }
    }
    // ---- x-part: K=128 from LDS over Wx1t ----
#pragma unroll
    for (int ks = 0; ks < 4; ++ks) {
      int k = ks * 32 + quad * 8;
      bf16x8 a = *(const bf16x8*)(xs + (wv * 16 + ln) * XP + k);
#pragma unroll
      for (int j = 0; j < 2; ++j) {
        az[j]  = MFMA16(a, *(const bf16x8*)(Wx1t + (size_t)(cz0 + j * 16 + ln) * KX + k), az[j]);
        ar[j]  = MFMA16(a, *(const bf16x8*)(Wx1t + (size_t)(cr0 + j * 16 + ln) * KX + k), ar[j]);
        anx[j] = MFMA16(a, *(const bf16x8*)(Wx1t + (size_t)(cn0 + j * 16 + ln) * KX + k), anx[j]);
      }
    }
  } else {
    // ---- layer 2: h-part K=512 (h2 state) ----
#pragma unroll 4
    for (int ks = 0; ks < 16; ++ks) {
      int k = ks * 32 + quad * 8;
      bf16x8 a = *(const bf16x8*)(h2r + (size_t)(rw + ln) * U + k);
#pragma unroll
      for (int j = 0; j < 2; ++j) {
        az[j]  = MFMA16(a, *(const bf16x8*)(Wh2t + (size_t)(cz0 + j * 16 + ln) * U + k), az[j]);
        ar[j]  = MFMA16(a, *(const bf16x8*)(Wh2t + (size_t)(cr0 + j * 16 + ln) * U + k), ar[j]);
        anh[j] = MFMA16(a, *(const bf16x8*)(Wh2t + (size_t)(cn0 + j * 16 + ln) * U + k), anh[j]);
      }
    }
    // ---- x-part K=512: x = ys1[t] = h1 state written at super-step s-1 ----
#pragma unroll 4
    for (int ks = 0; ks < 16; ++ks) {
      int k = ks * 32 + quad * 8;
      bf16x8 a = *(const bf16x8*)(h1r + (size_t)(rw + ln) * U + k);
#pragma unroll
      for (int j = 0; j < 2; ++j) {
        az[j]  = MFMA16(a, *(const bf16x8*)(Wx2t + (size_t)(cz0 + j * 16 + ln) * U + k), az[j]);
        ar[j]  = MFMA16(a, *(const bf16x8*)(Wx2t + (size_t)(cr0 + j * 16 + ln) * U + k), ar[j]);
        anx[j] = MFMA16(a, *(const bf16x8*)(Wx2t + (size_t)(cn0 + j * 16 + ln) * U + k), anx[j]);
      }
    }
  }

  // ---- gates + state update (C layout: col = lane&15, row = quad*4 + i) ----
  const float* bb = is2 ? b2 : b1;
  float* hf = is2 ? h2f : h1f;
  __bf16* hw = is2 ? h2w : h1w;
#pragma unroll
  for (int j = 0; j < 2; ++j) {
    int u = u0 + j * 16 + ln;
    float bz  = bb[u] + bb[G + u];
    float brr = bb[U + u] + bb[G + U + u];
    float bnx = bb[2 * U + u];
    float bnh = bb[G + 2 * U + u];
#pragma unroll
    for (int i = 0; i < 4; ++i) {
      size_t idx = (size_t)(rw + quad * 4 + i) * U + u;
      float z  = sigmoidf_(az[j][i] + bz);
      float r  = sigmoidf_(ar[j][i] + brr);
      float hh = tanhf(anx[j][i] + bnx + r * (anh[j][i] + bnh));
      float hn = z * hf[idx] + (1.f - z) * hh;
      hf[idx] = hn;
      hw[idx] = (__bf16)hn;
    }
  }
}

// out[b] = sigmoid(h2_final[b] . Wfc + bfc); one wave per row
__global__ void k_fc(const float* __restrict__ h2f, const float* __restrict__ Wfc,
                     const float* __restrict__ bfc, float* __restrict__ out) {
  int row = blockIdx.x * 4 + (threadIdx.x >> 6);
  int lane = threadIdx.x & 63;
  float s = 0.f;
#pragma unroll
  for (int k = lane; k < U; k += 64) s += h2f[(size_t)row * U + k] * Wfc[k];
#pragma unroll
  for (int off = 32; off; off >>= 1) s += __shfl_down(s, off, 64);
  if (lane == 0) out[row] = sigmoidf_(s + bfc[0]);
}

extern "C" void kernel_launch(void* const* d_in, const int* in_sizes, int n_in,
                              void* d_out, int out_size, void* d_ws, size_t ws_size,
                              hipStream_t stream) {
  const int*   tokens = (const int*)d_in[0];
  const float* emb = (const float*)d_in[1];
  const float* Wx1 = (const float*)d_in[2];
  const float* Wh1 = (const float*)d_in[3];
  const float* b1  = (const float*)d_in[4];
  const float* Wx2 = (const float*)d_in[5];
  const float* Wh2 = (const float*)d_in[6];
  const float* b2  = (const float*)d_in[7];
  const float* Wfc = (const float*)d_in[8];
  const float* bfc = (const float*)d_in[9];
  float* out = (float*)d_out;

  // ws layout (16B-aligned chunks)
  __bf16* Wx1t = (__bf16*)d_ws;                 // [1536][128]
  __bf16* Wh1t = Wx1t + 1536 * KX;              // [1536][512]
  __bf16* Wx2t = Wh1t + 1536 * U;               // [1536][512]
  __bf16* Wh2t = Wx2t + 1536 * U;               // [1536][512]
  __bf16* embp = Wh2t + 1536 * U;               // [10000][128]
  __bf16* h1b0 = embp + 10000 * KX;             // [1024][512] bf16 state buffers
  __bf16* h1b1 = h1b0 + BATCH * U;
  __bf16* h2b0 = h1b1 + BATCH * U;
  __bf16* h2b1 = h2b0 + BATCH * U;
  float*  h1f  = (float*)(h2b1 + BATCH * U);    // [1024][512] f32 states
  float*  h2f  = h1f + BATCH * U;

  // prep: transposed bf16 weights, padded bf16 embedding
  k_conv_transpose<<<(1536 * (KX / 8) + 255) / 256, 256, 0, stream>>>(Wx1, Wx1t, 1536, KX, EMB);
  k_conv_transpose<<<(1536 * (U / 8) + 255) / 256, 256, 0, stream>>>(Wh1, Wh1t, 1536, U, U);
  k_conv_transpose<<<(1536 * (U / 8) + 255) / 256, 256, 0, stream>>>(Wx2, Wx2t, 1536, U, U);
  k_conv_transpose<<<(1536 * (U / 8) + 255) / 256, 256, 0, stream>>>(Wh2, Wh2t, 1536, U, U);
  k_emb_pad<<<(10000 * KX + 255) / 256, 256, 0, stream>>>(emb, embp);

  // zero all h state (bf16 x4 + f32 x2 contiguous = 8 MB)
  hipMemsetAsync(h1b0, 0, (size_t)BATCH * U * (4 * 2 + 2 * 4), stream);

  __bf16* h1b[2] = {h1b0, h1b1};
  __bf16* h2b[2] = {h2b0, h2b1};
  for (int s = 0; s <= SEQ; ++s) {
    __bf16* h1wp = h1b[s & 1];
    __bf16* h1rp = h1b[(s + 1) & 1];
    __bf16* h2wp = h2b[(s + 1) & 1];
    __bf16* h2rp = h2b[s & 1];
    k_step<<<256, 512, 0, stream>>>(s, tokens, embp, Wx1t, Wh1t, Wx2t, Wh2t,
                                    b1, b2, h1rp, h1wp, h2rp, h2wp, h1f, h2f);
  }

  k_fc<<<BATCH / 4, 256, 0, stream>>>(h2f, Wfc, bfc, out);
}

// Round 3
// 2062.228 us; speedup vs baseline: 6.5143x; 2.1732x over previous
//
#include <hip/hip_runtime.h>
#include <hip/hip_bf16.h>
#include <math.h>

typedef __bf16 bf16x8 __attribute__((ext_vector_type(8)));
typedef float f32x4 __attribute__((ext_vector_type(4)));

#define MFMA16(a,b,c) __builtin_amdgcn_mfma_f32_16x16x32_bf16(a,b,c,0,0,0)

constexpr int BATCH = 1024, SEQ = 80, EMB = 100, U = 512;
constexpr int K1 = 640;    // layer-1 combined K: 512 (h) + 128 (emb, padded)
constexpr int K2 = 1024;   // layer-2 combined K: 512 (h2) + 512 (h1)
constexpr int S1 = 648;    // LDS row stride (elems): 1296B -> lane stagger 4 banks
constexpr int S2 = 1032;   // 2064B -> stagger 4 banks, conflict-free b128

__device__ __forceinline__ float sigmoidf_(float x) { return 1.f / (1.f + __expf(-x)); }

// out[n][k] (n in [0,1536), k in [0,Kp)): k<512 -> WH[k][n]; 512<=k<512+KXr -> WX[k-512][n]; else 0
__global__ void k_combine(const float* __restrict__ WH, const float* __restrict__ WX,
                          __bf16* __restrict__ out, int KXr, int Kp) {
  int idx = blockIdx.x * 256 + threadIdx.x;
  int total = 1536 * (Kp / 8);
  if (idx >= total) return;
  int n = idx % 1536;       // consecutive threads -> consecutive n: coalesced
  int kb = idx / 1536;
  bf16x8 v;
#pragma unroll
  for (int j = 0; j < 8; ++j) {
    int k = kb * 8 + j;
    float f = 0.f;
    if (k < 512) f = WH[(size_t)k * 1536 + n];
    else if (k - 512 < KXr) f = WX[(size_t)(k - 512) * 1536 + n];
    v[j] = (__bf16)f;
  }
  *(bf16x8*)(out + (size_t)n * Kp + kb * 8) = v;
}

// emb [10000][100] f32 -> [10000][128] bf16 zero-padded
__global__ void k_emb_pad(const float* __restrict__ in, __bf16* __restrict__ out) {
  int idx = blockIdx.x * 256 + threadIdx.x;
  if (idx >= 10000 * 128) return;
  int r = idx >> 7, c = idx & 127;
  out[idx] = (c < EMB) ? (__bf16)in[r * EMB + c] : (__bf16)0.f;
}

// Pipelined GRU super-step s. bid&4 ? layer-2 @ t=s-1 : layer-1 @ t=s
// (XCD swizzle: layer-1 on XCDs 0-3, layer-2 on 4-7 under round-robin bid%8 placement).
// Block tile: 256 rows x 48 gate-cols (16 units x {z,r,n}), combined-K GEMM.
// Weight tile staged to LDS once; B from LDS, A (h-state / emb) from global L2.
__global__ __launch_bounds__(512, 2)
void k_step(int s,
            const int* __restrict__ tokens, const __bf16* __restrict__ embp,
            const __bf16* __restrict__ W1c, const __bf16* __restrict__ W2c,
            const float* __restrict__ b1, const float* __restrict__ b2,
            const __bf16* __restrict__ h1r, __bf16* __restrict__ h1w,
            const __bf16* __restrict__ h2r, __bf16* __restrict__ h2w,
            float* __restrict__ h1f, float* __restrict__ h2f) {
  __shared__ __attribute__((aligned(16))) __bf16 wt[48 * S2];  // 99 KB max

  const int bid = blockIdx.x, tid = threadIdx.x;
  const bool is2 = (bid & 4) != 0;
  if (is2 ? (s == 0) : (s == SEQ)) return;
  const int lb = (bid >> 3) * 4 + (bid & 3);   // 0..127 within layer
  const int colg = lb & 31, rowg = lb >> 5;
  const int u0 = colg * 16, r0 = rowg * 256;

  // ---- stage weight tile into LDS (48 rows: z units, r units, n units) ----
  if (is2) {
    int c = tid & 127, rb = tid >> 7;  // 128 chunks of 16B per 2KB row, 4 rows/iter
#pragma unroll
    for (int i = 0; i < 12; ++i) {
      int row = i * 4 + rb;
      int col = (row >> 4) * U + u0 + (row & 15);
      *(bf16x8*)(wt + row * S2 + c * 8) = *(const bf16x8*)(W2c + (size_t)col * K2 + c * 8);
    }
  } else {
#pragma unroll
    for (int i = 0; i < 8; ++i) {
      int ch = i * 512 + tid;           // 48 rows x 80 chunks = 3840
      if (ch < 3840) {
        int row = ch / 80, c = ch % 80;
        int col = (row >> 4) * U + u0 + (row & 15);
        *(bf16x8*)(wt + row * S1 + c * 8) = *(const bf16x8*)(W1c + (size_t)col * K1 + c * 8);
      }
    }
  }
  __syncthreads();

  const int wv = tid >> 6, lane = tid & 63, ln = lane & 15, quad = lane >> 4;
  const int kq = quad * 8;
  const int rwA = r0 + wv * 32 + ln;    // A row for rowtile 0 (rowtile 1 = +16)

  f32x4 az[2], ar[2], ax[2], ah[2];
  const f32x4 z4 = {0.f, 0.f, 0.f, 0.f};
#pragma unroll
  for (int j = 0; j < 2; ++j) { az[j] = z4; ar[j] = z4; ax[j] = z4; ah[j] = z4; }

  if (is2) {
    // h-part: A = h2 state, W rows k in [0,512)
#pragma unroll 4
    for (int ks = 0; ks < 16; ++ks) {
      int k = ks * 32 + kq;
      bf16x8 a0 = *(const bf16x8*)(h2r + (size_t)rwA * U + k);
      bf16x8 a1 = *(const bf16x8*)(h2r + (size_t)(rwA + 16) * U + k);
      bf16x8 bz_ = *(const bf16x8*)(wt + (0 + ln) * S2 + k);
      bf16x8 br_ = *(const bf16x8*)(wt + (16 + ln) * S2 + k);
      bf16x8 bn_ = *(const bf16x8*)(wt + (32 + ln) * S2 + k);
      az[0] = MFMA16(a0, bz_, az[0]); az[1] = MFMA16(a1, bz_, az[1]);
      ar[0] = MFMA16(a0, br_, ar[0]); ar[1] = MFMA16(a1, br_, ar[1]);
      ah[0] = MFMA16(a0, bn_, ah[0]); ah[1] = MFMA16(a1, bn_, ah[1]);
    }
    // x-part: A = h1 (= ys1[t]), W rows k in [512,1024)
#pragma unroll 4
    for (int ks = 0; ks < 16; ++ks) {
      int k = ks * 32 + kq;
      bf16x8 a0 = *(const bf16x8*)(h1r + (size_t)rwA * U + k);
      bf16x8 a1 = *(const bf16x8*)(h1r + (size_t)(rwA + 16) * U + k);
      bf16x8 bz_ = *(const bf16x8*)(wt + (0 + ln) * S2 + 512 + k);
      bf16x8 br_ = *(const bf16x8*)(wt + (16 + ln) * S2 + 512 + k);
      bf16x8 bn_ = *(const bf16x8*)(wt + (32 + ln) * S2 + 512 + k);
      az[0] = MFMA16(a0, bz_, az[0]); az[1] = MFMA16(a1, bz_, az[1]);
      ar[0] = MFMA16(a0, br_, ar[0]); ar[1] = MFMA16(a1, br_, ar[1]);
      ax[0] = MFMA16(a0, bn_, ax[0]); ax[1] = MFMA16(a1, bn_, ax[1]);
    }
  } else {
    int tok0 = tokens[(size_t)rwA * SEQ + s];
    int tok1 = tokens[(size_t)(rwA + 16) * SEQ + s];
    // h-part: A = h1 state, W rows k in [0,512)
#pragma unroll 4
    for (int ks = 0; ks < 16; ++ks) {
      int k = ks * 32 + kq;
      bf16x8 a0 = *(const bf16x8*)(h1r + (size_t)rwA * U + k);
      bf16x8 a1 = *(const bf16x8*)(h1r + (size_t)(rwA + 16) * U + k);
      bf16x8 bz_ = *(const bf16x8*)(wt + (0 + ln) * S1 + k);
      bf16x8 br_ = *(const bf16x8*)(wt + (16 + ln) * S1 + k);
      bf16x8 bn_ = *(const bf16x8*)(wt + (32 + ln) * S1 + k);
      az[0] = MFMA16(a0, bz_, az[0]); az[1] = MFMA16(a1, bz_, az[1]);
      ar[0] = MFMA16(a0, br_, ar[0]); ar[1] = MFMA16(a1, br_, ar[1]);
      ah[0] = MFMA16(a0, bn_, ah[0]); ah[1] = MFMA16(a1, bn_, ah[1]);
    }
    // x-part: A = emb[token], W rows k in [512,640)
#pragma unroll
    for (int ks = 0; ks < 4; ++ks) {
      int k = ks * 32 + kq;
      bf16x8 a0 = *(const bf16x8*)(embp + (size_t)tok0 * 128 + k);
      bf16x8 a1 = *(const bf16x8*)(embp + (size_t)tok1 * 128 + k);
      bf16x8 bz_ = *(const bf16x8*)(wt + (0 + ln) * S1 + 512 + k);
      bf16x8 br_ = *(const bf16x8*)(wt + (16 + ln) * S1 + 512 + k);
      bf16x8 bn_ = *(const bf16x8*)(wt + (32 + ln) * S1 + 512 + k);
      az[0] = MFMA16(a0, bz_, az[0]); az[1] = MFMA16(a1, bz_, az[1]);
      ar[0] = MFMA16(a0, br_, ar[0]); ar[1] = MFMA16(a1, br_, ar[1]);
      ax[0] = MFMA16(a0, bn_, ax[0]); ax[1] = MFMA16(a1, bn_, ax[1]);
    }
  }

  // ---- gates + state update (C layout: col = ln, row = quad*4 + i) ----
  const float* bb = is2 ? b2 : b1;
  float* hf = is2 ? h2f : h1f;
  __bf16* hw = is2 ? h2w : h1w;
  const int u = u0 + ln;
  const float bz = bb[u] + bb[1536 + u];
  const float brr = bb[512 + u] + bb[1536 + 512 + u];
  const float bnx = bb[1024 + u];
  const float bnh = bb[1536 + 1024 + u];
#pragma unroll
  for (int rt = 0; rt < 2; ++rt)
#pragma unroll
    for (int i = 0; i < 4; ++i) {
      int row = r0 + wv * 32 + rt * 16 + quad * 4 + i;
      size_t idx = (size_t)row * U + u;
      float z = sigmoidf_(az[rt][i] + bz);
      float r = sigmoidf_(ar[rt][i] + brr);
      float hh = tanhf(ax[rt][i] + bnx + r * (ah[rt][i] + bnh));
      float hn = z * hf[idx] + (1.f - z) * hh;
      hf[idx] = hn;
      hw[idx] = (__bf16)hn;
    }
}

// out[b] = sigmoid(h2_final[b] . Wfc + bfc); one wave per row
__global__ void k_fc(const float* __restrict__ h2f, const float* __restrict__ Wfc,
                     const float* __restrict__ bfc, float* __restrict__ out) {
  int row = blockIdx.x * 4 + (threadIdx.x >> 6);
  int lane = threadIdx.x & 63;
  float s = 0.f;
#pragma unroll
  for (int k = lane; k < U; k += 64) s += h2f[(size_t)row * U + k] * Wfc[k];
#pragma unroll
  for (int off = 32; off; off >>= 1) s += __shfl_down(s, off, 64);
  if (lane == 0) out[row] = sigmoidf_(s + bfc[0]);
}

extern "C" void kernel_launch(void* const* d_in, const int* in_sizes, int n_in,
                              void* d_out, int out_size, void* d_ws, size_t ws_size,
                              hipStream_t stream) {
  const int*   tokens = (const int*)d_in[0];
  const float* emb = (const float*)d_in[1];
  const float* Wx1 = (const float*)d_in[2];
  const float* Wh1 = (const float*)d_in[3];
  const float* b1  = (const float*)d_in[4];
  const float* Wx2 = (const float*)d_in[5];
  const float* Wh2 = (const float*)d_in[6];
  const float* b2  = (const float*)d_in[7];
  const float* Wfc = (const float*)d_in[8];
  const float* bfc = (const float*)d_in[9];
  float* out = (float*)d_out;

  // ws layout
  __bf16* W1c  = (__bf16*)d_ws;                 // [1536][640]
  __bf16* W2c  = W1c + 1536 * K1;               // [1536][1024]
  __bf16* embp = W2c + 1536 * K2;               // [10000][128]
  __bf16* h1b0 = embp + 10000 * 128;            // bf16 state double-buffers
  __bf16* h1b1 = h1b0 + BATCH * U;
  __bf16* h2b0 = h1b1 + BATCH * U;
  __bf16* h2b1 = h2b0 + BATCH * U;
  float*  h1f  = (float*)(h2b1 + BATCH * U);    // f32 persistent states
  float*  h2f  = h1f + BATCH * U;

  k_combine<<<(1536 * (K1 / 8) + 255) / 256, 256, 0, stream>>>(Wh1, Wx1, W1c, EMB, K1);
  k_combine<<<(1536 * (K2 / 8) + 255) / 256, 256, 0, stream>>>(Wh2, Wx2, W2c, U, K2);
  k_emb_pad<<<(10000 * 128 + 255) / 256, 256, 0, stream>>>(emb, embp);

  // zero all h state (bf16 x4 + f32 x2 contiguous = 12 MB)
  hipMemsetAsync(h1b0, 0, (size_t)BATCH * U * (4 * 2 + 2 * 4), stream);

  __bf16* h1b[2] = {h1b0, h1b1};
  __bf16* h2b[2] = {h2b0, h2b1};
  for (int s = 0; s <= SEQ; ++s) {
    __bf16* h1wp = h1b[s & 1];
    __bf16* h1rp = h1b[(s + 1) & 1];
    __bf16* h2wp = h2b[(s + 1) & 1];
    __bf16* h2rp = h2b[s & 1];
    k_step<<<256, 512, 0, stream>>>(s, tokens, embp, W1c, W2c, b1, b2,
                                    h1rp, h1wp, h2rp, h2wp, h1f, h2f);
  }

  k_fc<<<BATCH / 4, 256, 0, stream>>>(h2f, Wfc, bfc, out);
}